// Round 8
// baseline (4777.377 us; speedup 1.0000x reference)
//
#include <hip/hip_runtime.h>
#include <hip/hip_cooperative_groups.h>

namespace cg = cooperative_groups;

#define IN_DIM 32
#define HID 128
#define DEG 16
#define APAD 168   // A-tile row stride (ushorts)
#define HPAD 136   // staging row stride
#define ZPAD 40
#define BMF 16     // fallback kernels' nodes/block

typedef short bf16x8 __attribute__((ext_vector_type(8)));
typedef float f32x4 __attribute__((ext_vector_type(4)));

__device__ __forceinline__ float sigf(float x)   { return 1.0f / (1.0f + __expf(-x)); }
__device__ __forceinline__ float tanhfast(float x) {
    x = fminf(fmaxf(x, -15.0f), 15.0f);
    float e2 = __expf(2.0f * x);
    return (e2 - 1.0f) / (e2 + 1.0f);
}
__device__ __forceinline__ float lreluf(float x) { return x > 0.0f ? x : 0.01f * x; }
__device__ __forceinline__ unsigned short f2bf(float f) {
    unsigned int u = __float_as_uint(f);
    unsigned int r = (u + 0x7fffu + ((u >> 16) & 1u)) >> 16;
    return (unsigned short)r;
}
__device__ __forceinline__ float bf2f(unsigned short h) {
    return __uint_as_float(((unsigned int)h) << 16);
}
__device__ __forceinline__ float bflo(unsigned int v) {
    return __uint_as_float((v & 0xffffu) << 16);
}
__device__ __forceinline__ float bfhi(unsigned int v) {
    return __uint_as_float(v & 0xffff0000u);
}
__device__ __forceinline__ f32x4 mfma16(bf16x8 a, bf16x8 b, f32x4 c) {
    return __builtin_amdgcn_mfma_f32_16x16x32_bf16(a, b, c, 0, 0, 0);
}

// ---------------- prep ----------------
__global__ void prep_kernel(const float* __restrict__ fc1, const float* __restrict__ attn1,
                            const float* __restrict__ fc2, const float* __restrict__ attn2,
                            const float* __restrict__ bih, const float* __restrict__ bhh,
                            float* __restrict__ va1, float* __restrict__ vd1,
                            float* __restrict__ va2, float* __restrict__ vd2,
                            float* __restrict__ br, float* __restrict__ bz,
                            float* __restrict__ bni, float* __restrict__ bnh)
{
    int j = threadIdx.x;  // 128
    float a1 = 0, d1 = 0, a2 = 0, d2 = 0;
    for (int c = 0; c < 128; ++c) {
        float w = fc1[c * HID + j];
        a1 += attn1[c] * w;
        d1 += attn1[128 + c] * w;
    }
    for (int c = 0; c < 32; ++c) {
        float w = fc2[c * HID + j];
        a2 += attn2[c] * w;
        d2 += attn2[32 + c] * w;
    }
    va1[j] = a1; vd1[j] = d1; va2[j] = a2; vd2[j] = d2;
    br[j]  = bih[j] + bhh[j];
    bz[j]  = bih[HID + j] + bhh[HID + j];
    bni[j] = bih[2 * HID + j];
    bnh[j] = bhh[2 * HID + j];
}

// ---------------- pack weights into B-fragment order ----------------
#define NG (5 * 32 * 64 * 8)
#define N1 (4 * 9 * 64 * 8)
#define N2 (4 * 3 * 64 * 8)
__global__ void pack_all_kernel(const float* __restrict__ Wih, const float* __restrict__ Whh,
                                const float* __restrict__ fc1, const float* __restrict__ va1,
                                const float* __restrict__ vd1, const float* __restrict__ fc2,
                                const float* __restrict__ va2, const float* __restrict__ vd2,
                                unsigned short* __restrict__ Wg, unsigned short* __restrict__ F1p,
                                unsigned short* __restrict__ F2p)
{
    int idx = blockIdx.x * 256 + threadIdx.x;
    if (idx < NG) {
        int j = idx & 7, lane = (idx >> 3) & 63, tile = idx >> 9;
        int ct = tile & 31, kc = tile >> 5;
        int c = ct * 16 + (lane & 15);
        int k = kc * 32 + (lane >> 4) * 8 + j;
        float v;
        if (c < 256)      v = (k < 32) ? Wih[(size_t)c * 32 + k] : Whh[(size_t)c * 128 + (k - 32)];
        else if (c < 384) v = (k < 32) ? Wih[(size_t)c * 32 + k] : 0.0f;
        else              v = (k < 32) ? 0.0f : Whh[(size_t)(c - 128) * 128 + (k - 32)];
        Wg[idx] = f2bf(v);
    } else if (idx < NG + N1) {
        int i1 = idx - NG;
        int j = i1 & 7, lane = (i1 >> 3) & 63, tile = i1 >> 9;
        int ct = tile % 9, kc = tile / 9;
        int c = ct * 16 + (lane & 15);
        int k = kc * 32 + (lane >> 4) * 8 + j;
        float v;
        if (c < 128)       v = fc1[(size_t)c * 128 + k];
        else if (c == 128) v = va1[k];
        else if (c == 129) v = vd1[k];
        else               v = 0.0f;
        F1p[i1] = f2bf(v);
    } else if (idx < NG + N1 + N2) {
        int i2 = idx - NG - N1;
        int j = i2 & 7, lane = (i2 >> 3) & 63, tile = i2 >> 9;
        int ct = tile % 3, kc = tile / 3;
        int c = ct * 16 + (lane & 15);
        int k = kc * 32 + (lane >> 4) * 8 + j;
        float v;
        if (c < 32)       v = fc2[(size_t)c * 128 + k];
        else if (c == 32) v = va2[k];
        else if (c == 33) v = vd2[k];
        else              v = 0.0f;
        F2p[i2] = f2bf(v);
    }
}

// =================== cooperative persistent rollout ===================
// 256 threads (4 waves), grid = ceil(N/32); block owns 2 tiles of 16 nodes.
// LDS: A2 (x|h per tile, persistent) + Ht + sE + aE = 16.75 KB.
__global__ __launch_bounds__(256, 3)
void rollout_kernel(const float* __restrict__ x0, const int* __restrict__ src,
                    const float* __restrict__ tarr,
                    const unsigned short* __restrict__ Wg,
                    const unsigned short* __restrict__ F1p,
                    const unsigned short* __restrict__ F2p,
                    const float* __restrict__ br, const float* __restrict__ bz,
                    const float* __restrict__ bni, const float* __restrict__ bnh,
                    unsigned short* __restrict__ z1, float* __restrict__ ps1,
                    float* __restrict__ pd1,
                    unsigned short* __restrict__ z2, float* __restrict__ ps2,
                    float* __restrict__ pd2, float* __restrict__ state,
                    float* __restrict__ out, int N, int T)
{
    cg::grid_group gridg = cg::this_grid();

    __shared__ unsigned short A2[2][16][APAD];  // persistent [x(32)|h(128)] per tile
    __shared__ unsigned short Ht[16][HPAD];     // h_new / G / z staging (per tile, reused)
    __shared__ int            sE[16][DEG];
    __shared__ float          aE[16][DEG];

    const int tid = threadIdx.x, lane = tid & 63, w = tid >> 6;  // 4 waves
    const int n0 = blockIdx.x * 32;
    const int row = lane & 15, kg = lane >> 4;
    const int rn = tid >> 4, le = tid & 15;     // 16 nodes x 16 lanes

    // ---- init: x,state from x0; h = 0; out[0,:,0:32] = x0 ----
    {
        int r = tid >> 3, seg = tid & 7;        // 32 rows x 8 float4
        int n = n0 + r;
        if (n < N) {
            float4 v = *(const float4*)(x0 + (size_t)n * IN_DIM + seg * 4);
            float* sp = state + (size_t)n * IN_DIM + seg * 4;
            sp[0] = v.x; sp[1] = v.y; sp[2] = v.z; sp[3] = v.w;
            unsigned short* ap = &A2[r >> 4][r & 15][seg * 4];
            ap[0] = f2bf(v.x); ap[1] = f2bf(v.y); ap[2] = f2bf(v.z); ap[3] = f2bf(v.w);
            *(float4*)(out + (size_t)n * (2 * IN_DIM) + seg * 4) = v;
        }
        bf16x8 zz = {0, 0, 0, 0, 0, 0, 0, 0};
        for (int idx = tid; idx < 32 * 16; idx += 256) {
            int r2 = idx >> 4, sg = idx & 15;
            *(bf16x8*)&A2[r2 >> 4][r2 & 15][32 + sg * 8] = zz;
        }
    }
    __syncthreads();

    for (int t = 0; t < T; ++t) {
        // ---------- gat2(t-1) + state update + out slabs ----------
        if (t > 0) {
            float dt = tarr[t] - tarr[t - 1];
            #pragma unroll 1
            for (int tl = 0; tl < 2; ++tl) {
                int i = n0 + tl * 16 + rn;
                int s = 0; float e = -3.0e38f;
                if (i < N) {
                    s = src[i * DEG + le];
                    e = lreluf(ps2[s] + pd2[i]);
                }
                float m = e;
                m = fmaxf(m, __shfl_xor(m, 8));
                m = fmaxf(m, __shfl_xor(m, 4));
                m = fmaxf(m, __shfl_xor(m, 2));
                m = fmaxf(m, __shfl_xor(m, 1));
                float ee = __expf(e - m);
                float sum = ee;
                sum += __shfl_xor(sum, 8);
                sum += __shfl_xor(sum, 4);
                sum += __shfl_xor(sum, 2);
                sum += __shfl_xor(sum, 1);
                sE[rn][le] = s;
                aE[rn][le] = ee / sum;
                __syncthreads();

                const int c2 = le * 2;
                float a0 = 0.0f, a1 = 0.0f;
                #pragma unroll
                for (int k = 0; k < DEG; ++k) {
                    int   sk = sE[rn][k];
                    float ak = aE[rn][k];
                    unsigned int v = *(const unsigned int*)(z2 + (size_t)sk * IN_DIM + c2);
                    a0 = fmaf(ak, bflo(v), a0);
                    a1 = fmaf(ak, bfhi(v), a1);
                }
                if (i < N) {
                    float sn0 = fmaf(dt, a0, state[(size_t)i * IN_DIM + c2]);
                    float sn1 = fmaf(dt, a1, state[(size_t)i * IN_DIM + c2 + 1]);
                    state[(size_t)i * IN_DIM + c2]     = sn0;
                    state[(size_t)i * IN_DIM + c2 + 1] = sn1;
                    size_t ob = ((size_t)(t - 1) * N + i) * (2 * IN_DIM);
                    out[ob + IN_DIM + c2]     = a0;
                    out[ob + IN_DIM + c2 + 1] = a1;
                    out[ob + (size_t)N * (2 * IN_DIM) + c2]     = sn0;
                    out[ob + (size_t)N * (2 * IN_DIM) + c2 + 1] = sn1;
                    A2[tl][rn][c2]     = f2bf(sn0);
                    A2[tl][rn][c2 + 1] = f2bf(sn1);
                }
                __syncthreads();
            }
        }

        // ---------- GRU + z1ext per tile ----------
        #pragma unroll 1
        for (int tl = 0; tl < 2; ++tl) {
            // GEMM1: gates[16 x 512]; wave w does ctq = w*2 + q
            #pragma unroll 1
            for (int q = 0; q < 2; ++q) {
                int ctq = w * 2 + q;
                f32x4 acc0 = {0,0,0,0}, acc1 = {0,0,0,0}, acc2 = {0,0,0,0}, acc3 = {0,0,0,0};
                #pragma unroll
                for (int kc = 0; kc < 5; ++kc) {
                    bf16x8 a = *(const bf16x8*)&A2[tl][row][kc * 32 + kg * 8];
                    const unsigned short* bp = Wg + ((size_t)(kc * 32 + ctq) * 64 + lane) * 8;
                    acc0 = mfma16(a, *(const bf16x8*)(bp), acc0);
                    acc1 = mfma16(a, *(const bf16x8*)(bp + (size_t)8  * 64 * 8), acc1);
                    acc2 = mfma16(a, *(const bf16x8*)(bp + (size_t)16 * 64 * 8), acc2);
                    acc3 = mfma16(a, *(const bf16x8*)(bp + (size_t)24 * 64 * 8), acc3);
                }
                int col = ctq * 16 + row;
                float brv = br[col], bzv = bz[col], bniv = bni[col], bnhv = bnh[col];
                #pragma unroll
                for (int rr = 0; rr < 4; ++rr) {
                    int r_loc = kg * 4 + rr;
                    float rg = sigf(acc0[rr] + brv);
                    float zg = sigf(acc1[rr] + bzv);
                    float nc = tanhfast(acc2[rr] + bniv + rg * (acc3[rr] + bnhv));
                    float hold = bf2f(A2[tl][r_loc][32 + col]);
                    Ht[r_loc][col] = f2bf((1.0f - zg) * nc + zg * hold);
                }
            }
            __syncthreads();

            // copy h_new -> A2 (persistent) while GEMM2 accumulates from Ht
            *(bf16x8*)&A2[tl][rn][32 + le * 8] = *(const bf16x8*)&Ht[rn][le * 8];

            // GEMM2: z1ext[16 x 144]; wave w: ct = w, w+4, (w==0: 8)
            f32x4 za0 = {0,0,0,0}, za1 = {0,0,0,0}, za2 = {0,0,0,0};
            #pragma unroll
            for (int kc = 0; kc < 4; ++kc) {
                bf16x8 a = *(const bf16x8*)&Ht[row][kc * 32 + kg * 8];
                za0 = mfma16(a, *(const bf16x8*)(F1p + ((size_t)(kc * 9 + w)     * 64 + lane) * 8), za0);
                za1 = mfma16(a, *(const bf16x8*)(F1p + ((size_t)(kc * 9 + w + 4) * 64 + lane) * 8), za1);
                if (w == 0)
                    za2 = mfma16(a, *(const bf16x8*)(F1p + ((size_t)(kc * 9 + 8) * 64 + lane) * 8), za2);
            }
            __syncthreads();

            // write z1-tile into Ht (dead) + ps1/pd1 scalars
            {
                int col0 = w * 16 + row;          // 0..63
                int col1 = (w + 4) * 16 + row;    // 64..127
                #pragma unroll
                for (int rr = 0; rr < 4; ++rr) {
                    int r_loc = kg * 4 + rr;
                    Ht[r_loc][col0] = f2bf(za0[rr]);
                    Ht[r_loc][col1] = f2bf(za1[rr]);
                }
                if (w == 0 && row < 2) {
                    #pragma unroll
                    for (int rr = 0; rr < 4; ++rr) {
                        int n = n0 + tl * 16 + kg * 4 + rr;
                        if (n < N) {
                            if (row == 0) ps1[n] = za2[rr];
                            else          pd1[n] = za2[rr];
                        }
                    }
                }
            }
            __syncthreads();

            // z1 coalesced store
            {
                int n = n0 + tl * 16 + rn;
                if (n < N) *(bf16x8*)(z1 + (size_t)n * HID + le * 8) = *(const bf16x8*)&Ht[rn][le * 8];
            }
            __syncthreads();
        }
        __threadfence();
        gridg.sync();

        // ---------- gat1 + z2ext per tile ----------
        #pragma unroll 1
        for (int tl = 0; tl < 2; ++tl) {
            int i = n0 + tl * 16 + rn;
            int s = 0; float e = -3.0e38f;
            if (i < N) {
                s = src[i * DEG + le];
                e = lreluf(ps1[s] + pd1[i]);
            }
            float m = e;
            m = fmaxf(m, __shfl_xor(m, 8));
            m = fmaxf(m, __shfl_xor(m, 4));
            m = fmaxf(m, __shfl_xor(m, 2));
            m = fmaxf(m, __shfl_xor(m, 1));
            float ee = __expf(e - m);
            float sum = ee;
            sum += __shfl_xor(sum, 8);
            sum += __shfl_xor(sum, 4);
            sum += __shfl_xor(sum, 2);
            sum += __shfl_xor(sum, 1);
            sE[rn][le] = s;
            aE[rn][le] = ee / sum;
            __syncthreads();

            // aggregate -> Ht (G), relu fused
            {
                const int c8 = le * 8;
                float ac[8] = {0, 0, 0, 0, 0, 0, 0, 0};
                #pragma unroll
                for (int k = 0; k < DEG; ++k) {
                    int   sk = sE[rn][k];
                    float ak = aE[rn][k];
                    const unsigned int* zp = (const unsigned int*)(z1 + (size_t)sk * HID + c8);
                    unsigned int v0 = zp[0], v1 = zp[1], v2 = zp[2], v3 = zp[3];
                    ac[0] = fmaf(ak, bflo(v0), ac[0]);
                    ac[1] = fmaf(ak, bfhi(v0), ac[1]);
                    ac[2] = fmaf(ak, bflo(v1), ac[2]);
                    ac[3] = fmaf(ak, bfhi(v1), ac[3]);
                    ac[4] = fmaf(ak, bflo(v2), ac[4]);
                    ac[5] = fmaf(ak, bfhi(v2), ac[5]);
                    ac[6] = fmaf(ak, bflo(v3), ac[6]);
                    ac[7] = fmaf(ak, bfhi(v3), ac[7]);
                }
                #pragma unroll
                for (int j = 0; j < 8; ++j) Ht[rn][c8 + j] = f2bf(fmaxf(ac[j], 0.0f));
            }
            __syncthreads();

            // GEMM3: z2ext[16 x 48]; wave w<3 does ct=w
            f32x4 zb = {0, 0, 0, 0};
            if (w < 3) {
                #pragma unroll
                for (int kc = 0; kc < 4; ++kc) {
                    bf16x8 a = *(const bf16x8*)&Ht[row][kc * 32 + kg * 8];
                    zb = mfma16(a, *(const bf16x8*)(F2p + ((size_t)(kc * 3 + w) * 64 + lane) * 8), zb);
                }
            }
            __syncthreads();

            if (w < 3) {
                int col = w * 16 + row;
                #pragma unroll
                for (int rr = 0; rr < 4; ++rr) {
                    int r_loc = kg * 4 + rr;
                    int n = n0 + tl * 16 + r_loc;
                    if (col < 32)                Ht[r_loc][col] = f2bf(zb[rr]);
                    else if (n < N && col == 32) ps2[n] = zb[rr];
                    else if (n < N && col == 33) pd2[n] = zb[rr];
                }
            }
            __syncthreads();

            if (tid < 64) {
                int r = tid >> 2, sg = tid & 3, n = n0 + tl * 16 + r;
                if (n < N) *(bf16x8*)(z2 + (size_t)n * IN_DIM + sg * 8) = *(const bf16x8*)&Ht[r][sg * 8];
            }
            __syncthreads();
        }
        __threadfence();
        gridg.sync();
    }

    // ---------- tail: gat2 for t = T-1, xii only ----------
    #pragma unroll 1
    for (int tl = 0; tl < 2; ++tl) {
        int i = n0 + tl * 16 + rn;
        int s = 0; float e = -3.0e38f;
        if (i < N) {
            s = src[i * DEG + le];
            e = lreluf(ps2[s] + pd2[i]);
        }
        float m = e;
        m = fmaxf(m, __shfl_xor(m, 8));
        m = fmaxf(m, __shfl_xor(m, 4));
        m = fmaxf(m, __shfl_xor(m, 2));
        m = fmaxf(m, __shfl_xor(m, 1));
        float ee = __expf(e - m);
        float sum = ee;
        sum += __shfl_xor(sum, 8);
        sum += __shfl_xor(sum, 4);
        sum += __shfl_xor(sum, 2);
        sum += __shfl_xor(sum, 1);
        sE[rn][le] = s;
        aE[rn][le] = ee / sum;
        __syncthreads();

        const int c2 = le * 2;
        float a0 = 0.0f, a1 = 0.0f;
        #pragma unroll
        for (int k = 0; k < DEG; ++k) {
            int   sk = sE[rn][k];
            float ak = aE[rn][k];
            unsigned int v = *(const unsigned int*)(z2 + (size_t)sk * IN_DIM + c2);
            a0 = fmaf(ak, bflo(v), a0);
            a1 = fmaf(ak, bfhi(v), a1);
        }
        if (i < N) {
            size_t ob = ((size_t)(T - 1) * N + i) * (2 * IN_DIM);
            out[ob + IN_DIM + c2]     = a0;
            out[ob + IN_DIM + c2 + 1] = a1;
        }
        __syncthreads();
    }
}

// =================== fallback path (R6, proven) ===================
__global__ void init_kernel(const float* __restrict__ x0, float* __restrict__ state,
                            unsigned short* __restrict__ state_bf, unsigned short* __restrict__ hA,
                            float* __restrict__ out, int N)
{
    int i = blockIdx.x * 256 + threadIdx.x;
    if (i < N * HID) hA[i] = 0;
    if (i < N * IN_DIM) {
        float v = x0[i];
        state[i] = v;
        state_bf[i] = f2bf(v);
        int n = i >> 5, c = i & 31;
        out[(size_t)n * (2 * IN_DIM) + c] = v;
    }
}

__global__ __launch_bounds__(256)
void kA(const unsigned short* __restrict__ xbf, const unsigned short* __restrict__ hin,
        unsigned short* __restrict__ hout,
        const unsigned short* __restrict__ Wg, const unsigned short* __restrict__ Fc1,
        const float* __restrict__ br, const float* __restrict__ bz,
        const float* __restrict__ bni, const float* __restrict__ bnh,
        unsigned short* __restrict__ z1, float* __restrict__ ps1, float* __restrict__ pd1,
        const unsigned short* __restrict__ z2, const float* __restrict__ ps2,
        const float* __restrict__ pd2, const int* __restrict__ src,
        float* __restrict__ state, float* __restrict__ out, const float* __restrict__ tarr,
        int tstep, int N, int T)
{
    __shared__ unsigned short A[BMF][APAD];
    __shared__ unsigned short Ht[BMF][HPAD];
    __shared__ int   sE[BMF][DEG];
    __shared__ float aE[BMF][DEG];

    const int tid = threadIdx.x, lane = tid & 63, w = tid >> 6;
    const int n0 = blockIdx.x * BMF;
    const int row = lane & 15, kg = lane >> 4;
    const int rn = tid >> 4, le = tid & 15;

    {
        int n = n0 + rn;
        bf16x8 v = {0, 0, 0, 0, 0, 0, 0, 0};
        if (n < N) v = *(const bf16x8*)(hin + (size_t)n * HID + le * 8);
        *(bf16x8*)&A[rn][32 + le * 8] = v;
    }

    if (tstep == 0) {
        if (tid < BMF * 4) {
            int r = tid >> 2, seg = tid & 3, n = n0 + r;
            bf16x8 v = {0, 0, 0, 0, 0, 0, 0, 0};
            if (n < N) v = *(const bf16x8*)(xbf + (size_t)n * IN_DIM + seg * 8);
            *(bf16x8*)&A[r][seg * 8] = v;
        }
    } else {
        {
            int i = n0 + rn;
            int s = 0; float e = -3.0e38f;
            if (i < N) {
                s = src[i * DEG + le];
                e = lreluf(ps2[s] + pd2[i]);
            }
            float m = e;
            m = fmaxf(m, __shfl_xor(m, 8));
            m = fmaxf(m, __shfl_xor(m, 4));
            m = fmaxf(m, __shfl_xor(m, 2));
            m = fmaxf(m, __shfl_xor(m, 1));
            float ee = __expf(e - m);
            float sum = ee;
            sum += __shfl_xor(sum, 8);
            sum += __shfl_xor(sum, 4);
            sum += __shfl_xor(sum, 2);
            sum += __shfl_xor(sum, 1);
            sE[rn][le] = s;
            aE[rn][le] = ee / sum;
        }
        __syncthreads();
        {
            const int c2 = le * 2;
            float a0 = 0.0f, a1 = 0.0f;
            #pragma unroll
            for (int k = 0; k < DEG; ++k) {
                int   s = sE[rn][k];
                float a = aE[rn][k];
                unsigned int v = *(const unsigned int*)(z2 + (size_t)s * IN_DIM + c2);
                a0 = fmaf(a, bflo(v), a0);
                a1 = fmaf(a, bfhi(v), a1);
            }
            int i = n0 + rn;
            if (i < N) {
                float dt = tarr[tstep] - tarr[tstep - 1];
                float sn0 = fmaf(dt, a0, state[(size_t)i * IN_DIM + c2]);
                float sn1 = fmaf(dt, a1, state[(size_t)i * IN_DIM + c2 + 1]);
                state[(size_t)i * IN_DIM + c2]     = sn0;
                state[(size_t)i * IN_DIM + c2 + 1] = sn1;
                size_t ob = ((size_t)(tstep - 1) * N + i) * (2 * IN_DIM);
                out[ob + IN_DIM + c2]     = a0;
                out[ob + IN_DIM + c2 + 1] = a1;
                out[ob + (size_t)N * (2 * IN_DIM) + c2]     = sn0;
                out[ob + (size_t)N * (2 * IN_DIM) + c2 + 1] = sn1;
                A[rn][c2]     = f2bf(sn0);
                A[rn][c2 + 1] = f2bf(sn1);
            }
        }
    }
    __syncthreads();

    #pragma unroll 1
    for (int q = 0; q < 2; ++q) {
        int ctq = w * 2 + q;
        f32x4 acc0 = {0,0,0,0}, acc1 = {0,0,0,0}, acc2 = {0,0,0,0}, acc3 = {0,0,0,0};
        #pragma unroll
        for (int kc = 0; kc < 5; ++kc) {
            bf16x8 a = *(const bf16x8*)&A[row][kc * 32 + kg * 8];
            const unsigned short* bp = Wg + ((size_t)(kc * 32 + ctq) * 64 + lane) * 8;
            acc0 = mfma16(a, *(const bf16x8*)(bp), acc0);
            acc1 = mfma16(a, *(const bf16x8*)(bp + (size_t)8  * 64 * 8), acc1);
            acc2 = mfma16(a, *(const bf16x8*)(bp + (size_t)16 * 64 * 8), acc2);
            acc3 = mfma16(a, *(const bf16x8*)(bp + (size_t)24 * 64 * 8), acc3);
        }
        int col = ctq * 16 + row;
        float brv = br[col], bzv = bz[col], bniv = bni[col], bnhv = bnh[col];
        #pragma unroll
        for (int rr = 0; rr < 4; ++rr) {
            int r_loc = kg * 4 + rr;
            float rg = sigf(acc0[rr] + brv);
            float zg = sigf(acc1[rr] + bzv);
            float nc = tanhfast(acc2[rr] + bniv + rg * (acc3[rr] + bnhv));
            float hold = bf2f(A[r_loc][32 + col]);
            Ht[r_loc][col] = f2bf((1.0f - zg) * nc + zg * hold);
        }
    }
    __syncthreads();

    {
        int n = n0 + rn;
        if (n < N) *(bf16x8*)(hout + (size_t)n * HID + le * 8) = *(const bf16x8*)&Ht[rn][le * 8];
    }

    #pragma unroll 1
    for (int ct = w; ct < 9; ct += 4) {
        f32x4 acc = {0, 0, 0, 0};
        #pragma unroll
        for (int kc = 0; kc < 4; ++kc) {
            bf16x8 a = *(const bf16x8*)&Ht[row][kc * 32 + kg * 8];
            bf16x8 b = *(const bf16x8*)(Fc1 + ((size_t)(kc * 9 + ct) * 64 + lane) * 8);
            acc = mfma16(a, b, acc);
        }
        int col = ct * 16 + row;
        #pragma unroll
        for (int rr = 0; rr < 4; ++rr) {
            int r_loc = kg * 4 + rr;
            int n = n0 + r_loc;
            if (col < 128)                A[r_loc][col] = f2bf(acc[rr]);
            else if (n < N && col == 128) ps1[n] = acc[rr];
            else if (n < N && col == 129) pd1[n] = acc[rr];
        }
    }
    __syncthreads();

    {
        int n = n0 + rn;
        if (n < N) *(bf16x8*)(z1 + (size_t)n * HID + le * 8) = *(const bf16x8*)&A[rn][le * 8];
    }
}

__global__ __launch_bounds__(256)
void kB(const unsigned short* __restrict__ z1, const float* __restrict__ ps1,
        const float* __restrict__ pd1, const int* __restrict__ src,
        const unsigned short* __restrict__ Fc2,
        unsigned short* __restrict__ z2, float* __restrict__ ps2,
        float* __restrict__ pd2, int N)
{
    __shared__ unsigned short G[BMF][HPAD];
    __shared__ unsigned short Z[BMF][ZPAD];
    __shared__ int   sE[BMF][DEG];
    __shared__ float aE[BMF][DEG];

    const int tid = threadIdx.x, lane = tid & 63, w = tid >> 6;
    const int n0 = blockIdx.x * BMF;
    const int row = lane & 15, kg = lane >> 4;
    const int rn = tid >> 4, le = tid & 15;

    {
        int i = n0 + rn;
        int s = 0; float e = -3.0e38f;
        if (i < N) {
            s = src[i * DEG + le];
            e = lreluf(ps1[s] + pd1[i]);
        }
        float m = e;
        m = fmaxf(m, __shfl_xor(m, 8));
        m = fmaxf(m, __shfl_xor(m, 4));
        m = fmaxf(m, __shfl_xor(m, 2));
        m = fmaxf(m, __shfl_xor(m, 1));
        float ee = __expf(e - m);
        float sum = ee;
        sum += __shfl_xor(sum, 8);
        sum += __shfl_xor(sum, 4);
        sum += __shfl_xor(sum, 2);
        sum += __shfl_xor(sum, 1);
        sE[rn][le] = s;
        aE[rn][le] = ee / sum;
    }
    __syncthreads();

    {
        const int c8 = le * 8;
        float ac[8] = {0, 0, 0, 0, 0, 0, 0, 0};
        #pragma unroll
        for (int k = 0; k < DEG; ++k) {
            int   s = sE[rn][k];
            float a = aE[rn][k];
            const unsigned int* zp = (const unsigned int*)(z1 + (size_t)s * HID + c8);
            unsigned int v0 = zp[0], v1 = zp[1], v2 = zp[2], v3 = zp[3];
            ac[0] = fmaf(a, bflo(v0), ac[0]);
            ac[1] = fmaf(a, bfhi(v0), ac[1]);
            ac[2] = fmaf(a, bflo(v1), ac[2]);
            ac[3] = fmaf(a, bfhi(v1), ac[3]);
            ac[4] = fmaf(a, bflo(v2), ac[4]);
            ac[5] = fmaf(a, bfhi(v2), ac[5]);
            ac[6] = fmaf(a, bflo(v3), ac[6]);
            ac[7] = fmaf(a, bfhi(v3), ac[7]);
        }
        #pragma unroll
        for (int j = 0; j < 8; ++j) G[rn][c8 + j] = f2bf(fmaxf(ac[j], 0.0f));
    }
    __syncthreads();

    if (w < 3) {
        int ct = w;
        f32x4 acc = {0, 0, 0, 0};
        #pragma unroll
        for (int kc = 0; kc < 4; ++kc) {
            bf16x8 a = *(const bf16x8*)&G[row][kc * 32 + kg * 8];
            bf16x8 b = *(const bf16x8*)(Fc2 + ((size_t)(kc * 3 + ct) * 64 + lane) * 8);
            acc = mfma16(a, b, acc);
        }
        int col = ct * 16 + row;
        #pragma unroll
        for (int rr = 0; rr < 4; ++rr) {
            int r_loc = kg * 4 + rr;
            int n = n0 + r_loc;
            if (col < 32)                Z[r_loc][col] = f2bf(acc[rr]);
            else if (n < N && col == 32) ps2[n] = acc[rr];
            else if (n < N && col == 33) pd2[n] = acc[rr];
        }
    }
    __syncthreads();

    if (tid < BMF * 4) {
        int r = tid >> 2, seg = tid & 3, n = n0 + r;
        if (n < N) *(bf16x8*)(z2 + (size_t)n * IN_DIM + seg * 8) = *(const bf16x8*)&Z[r][seg * 8];
    }
}

__global__ __launch_bounds__(256)
void kTail(const unsigned short* __restrict__ z2, const float* __restrict__ ps2,
           const float* __restrict__ pd2, const int* __restrict__ src,
           float* __restrict__ out, int N, int T)
{
    __shared__ int   sE[BMF][DEG];
    __shared__ float aE[BMF][DEG];
    const int tid = threadIdx.x;
    const int n0 = blockIdx.x * BMF;
    const int rn = tid >> 4, le = tid & 15;

    {
        int i = n0 + rn;
        int s = 0; float e = -3.0e38f;
        if (i < N) {
            s = src[i * DEG + le];
            e = lreluf(ps2[s] + pd2[i]);
        }
        float m = e;
        m = fmaxf(m, __shfl_xor(m, 8));
        m = fmaxf(m, __shfl_xor(m, 4));
        m = fmaxf(m, __shfl_xor(m, 2));
        m = fmaxf(m, __shfl_xor(m, 1));
        float ee = __expf(e - m);
        float sum = ee;
        sum += __shfl_xor(sum, 8);
        sum += __shfl_xor(sum, 4);
        sum += __shfl_xor(sum, 2);
        sum += __shfl_xor(sum, 1);
        sE[rn][le] = s;
        aE[rn][le] = ee / sum;
    }
    __syncthreads();

    {
        const int c2 = le * 2;
        float a0 = 0.0f, a1 = 0.0f;
        #pragma unroll
        for (int k = 0; k < DEG; ++k) {
            int   s = sE[rn][k];
            float a = aE[rn][k];
            unsigned int v = *(const unsigned int*)(z2 + (size_t)s * IN_DIM + c2);
            a0 = fmaf(a, bflo(v), a0);
            a1 = fmaf(a, bfhi(v), a1);
        }
        int i = n0 + rn;
        if (i < N) {
            size_t ob = ((size_t)(T - 1) * N + i) * (2 * IN_DIM);
            out[ob + IN_DIM + c2]     = a0;
            out[ob + IN_DIM + c2 + 1] = a1;
        }
    }
}

extern "C" void kernel_launch(void* const* d_in, const int* in_sizes, int n_in,
                              void* d_out, int out_size, void* d_ws, size_t ws_size,
                              hipStream_t stream)
{
    const float* tarr  = (const float*)d_in[0];
    const float* x0    = (const float*)d_in[1];
    const int*   src   = (const int*)d_in[2];
    // d_in[3] = dst (structural: repeat(arange(N), DEG))
    const float* Wih   = (const float*)d_in[4];
    const float* Whh   = (const float*)d_in[5];
    const float* bih   = (const float*)d_in[6];
    const float* bhh   = (const float*)d_in[7];
    const float* fc1   = (const float*)d_in[8];
    const float* attn1 = (const float*)d_in[9];
    const float* fc2   = (const float*)d_in[10];
    const float* attn2 = (const float*)d_in[11];
    float* out = (float*)d_out;

    int T = in_sizes[0];
    int N = in_sizes[1] / IN_DIM;

    // f32 region
    float* fp = (float*)d_ws;
    float* ps1 = fp; fp += N;
    float* pd1 = fp; fp += N;
    float* ps2 = fp; fp += N;
    float* pd2 = fp; fp += N;
    float* va1 = fp; fp += HID;
    float* vd1 = fp; fp += HID;
    float* va2 = fp; fp += HID;
    float* vd2 = fp; fp += HID;
    float* br  = fp; fp += HID;
    float* bz  = fp; fp += HID;
    float* bni = fp; fp += HID;
    float* bnh = fp; fp += HID;
    float* state = fp; fp += (size_t)N * IN_DIM;
    // bf16 region
    unsigned short* up = (unsigned short*)fp;
    unsigned short* state_bf = up; up += (size_t)N * IN_DIM;
    unsigned short* hA  = up; up += (size_t)N * HID;
    unsigned short* hB  = up; up += (size_t)N * HID;
    unsigned short* z1  = up; up += (size_t)N * HID;
    unsigned short* z2  = up; up += (size_t)N * IN_DIM;
    unsigned short* Wg  = up; up += NG;
    unsigned short* F1p = up; up += N1;
    unsigned short* F2p = up; up += N2;

    prep_kernel<<<1, 128, 0, stream>>>(fc1, attn1, fc2, attn2, bih, bhh,
                                       va1, vd1, va2, vd2, br, bz, bni, bnh);
    pack_all_kernel<<<(NG + N1 + N2 + 255) / 256, 256, 0, stream>>>(
        Wih, Whh, fc1, va1, vd1, fc2, va2, vd2, Wg, F1p, F2p);

    // ---- try cooperative persistent kernel ----
    const int nblk_coop = (N + 31) / 32;   // 625 for N=20000
    void* args[] = {
        (void*)&x0, (void*)&src, (void*)&tarr,
        (void*)&Wg, (void*)&F1p, (void*)&F2p,
        (void*)&br, (void*)&bz, (void*)&bni, (void*)&bnh,
        (void*)&z1, (void*)&ps1, (void*)&pd1,
        (void*)&z2, (void*)&ps2, (void*)&pd2,
        (void*)&state, (void*)&out, (void*)&N, (void*)&T
    };
    hipError_t cerr = hipLaunchCooperativeKernel((void*)rollout_kernel,
                                                 dim3(nblk_coop), dim3(256),
                                                 args, 0, stream);
    if (cerr != hipSuccess) {
        // ---- fallback: proven multi-kernel path ----
        const int nblk = (N + BMF - 1) / BMF;
        init_kernel<<<(N * HID + 255) / 256, 256, 0, stream>>>(x0, state, state_bf, hA, out, N);
        for (int t = 0; t < T; ++t) {
            const unsigned short* hin   = (t & 1) ? hB : hA;
            unsigned short*       houtp = (t & 1) ? hA : hB;
            kA<<<nblk, 256, 0, stream>>>(state_bf, hin, houtp, Wg, F1p,
                                         br, bz, bni, bnh, z1, ps1, pd1,
                                         z2, ps2, pd2, src, state, out, tarr, t, N, T);
            kB<<<nblk, 256, 0, stream>>>(z1, ps1, pd1, src, F2p, z2, ps2, pd2, N);
        }
        kTail<<<nblk, 256, 0, stream>>>(z2, ps2, pd2, src, out, N, T);
    }
}